// Round 1
// baseline (377.486 us; speedup 1.0000x reference)
//
#include <hip/hip_runtime.h>

// Problem constants (from reference): x = (32, 256, 56, 56) fp32
#define M_BATCH 32
#define D_FEAT 256
#define HW 3136              // 56*56
#define NGROUPS 16
#define GS 16
#define NTOT (M_BATCH * HW)  // 100352 samples per channel
#define TRI 136              // 16*17/2 packed lower triangle
#define EPS_W 1e-6f

__device__ __host__ constexpr int tidx(int i, int j) { return i * (i + 1) / 2 + j; }

// ---------------------------------------------------------------------------
// Pass 1: per-channel sums + per-group packed Gram (x xT) accumulators.
// One block per (batch, group); each thread owns whole 16-channel columns.
// ---------------------------------------------------------------------------
__global__ __launch_bounds__(256, 2) void whiten_stats(const float* __restrict__ x,
                                                       float* __restrict__ sums,
                                                       float* __restrict__ gram) {
    const int b = blockIdx.x;
    const int g = blockIdx.y;
    const float* base = x + ((size_t)b * D_FEAT + (size_t)g * GS) * HW;

    float s[GS];
    float acc[TRI];
#pragma unroll
    for (int j = 0; j < GS; ++j) s[j] = 0.0f;
#pragma unroll
    for (int k = 0; k < TRI; ++k) acc[k] = 0.0f;

    for (int p = threadIdx.x; p < HW; p += 256) {
        float v[GS];
#pragma unroll
        for (int j = 0; j < GS; ++j) v[j] = base[(size_t)j * HW + p];
#pragma unroll
        for (int i = 0; i < GS; ++i) {
            s[i] += v[i];
#pragma unroll
            for (int j = 0; j <= i; ++j)
                acc[tidx(i, j)] = fmaf(v[i], v[j], acc[tidx(i, j)]);
        }
    }

    // wave(64)-level shuffle reduction, then one atomic per wave per cell
    const int lane = threadIdx.x & 63;
#pragma unroll
    for (int j = 0; j < GS; ++j) {
        float v = s[j];
#pragma unroll
        for (int off = 32; off > 0; off >>= 1) v += __shfl_down(v, off, 64);
        if (lane == 0) atomicAdd(&sums[g * GS + j], v);
    }
#pragma unroll
    for (int k = 0; k < TRI; ++k) {
        float v = acc[k];
#pragma unroll
        for (int off = 32; off > 0; off >>= 1) v += __shfl_down(v, off, 64);
        if (lane == 0) atomicAdd(&gram[g * TRI + k], v);
    }
}

// ---------------------------------------------------------------------------
// Pass 2: sigma -> Cholesky -> inv(T), all 16 groups in parallel lanes of one
// wave. Packed lower-triangular, fully unrolled -> registers.
// ---------------------------------------------------------------------------
__global__ void whiten_solve(const float* __restrict__ sums,
                             const float* __restrict__ gram,
                             float* __restrict__ wout,
                             float* __restrict__ muout) {
    const int g = threadIdx.x;
    if (g >= NGROUPS) return;

    float mu[GS];
#pragma unroll
    for (int j = 0; j < GS; ++j) mu[j] = sums[g * GS + j] * (1.0f / (float)NTOT);

    float S[TRI];
#pragma unroll
    for (int i = 0; i < GS; ++i) {
#pragma unroll
        for (int j = 0; j <= i; ++j) {
            float sg = (gram[g * TRI + tidx(i, j)] - (float)NTOT * mu[i] * mu[j])
                       * (1.0f / (float)(NTOT - 1));
            sg *= (1.0f - EPS_W);
            if (i == j) sg += EPS_W;
            S[tidx(i, j)] = sg;
        }
    }

    // In-place Cholesky (Crout, column-by-column): S becomes T (lower).
#pragma unroll
    for (int c = 0; c < GS; ++c) {
        float d = S[tidx(c, c)];
#pragma unroll
        for (int k = 0; k < c; ++k) d -= S[tidx(c, k)] * S[tidx(c, k)];
        d = sqrtf(d);
        S[tidx(c, c)] = d;
        const float inv = 1.0f / d;
#pragma unroll
        for (int i = c + 1; i < GS; ++i) {
            float t = S[tidx(i, c)];
#pragma unroll
            for (int k = 0; k < c; ++k) t -= S[tidx(i, k)] * S[tidx(c, k)];
            S[tidx(i, c)] = t * inv;
        }
    }

    // In-place inverse of lower-triangular T: S becomes W = T^{-1}.
    // Column c left->right; T[i][k] (k>=c) still original when consumed.
#pragma unroll
    for (int c = 0; c < GS; ++c) {
        const float wcc = 1.0f / S[tidx(c, c)];
        S[tidx(c, c)] = wcc;
#pragma unroll
        for (int i = c + 1; i < GS; ++i) {
            float a = 0.0f;
#pragma unroll
            for (int k = c; k < i; ++k) a += S[tidx(i, k)] * S[tidx(k, c)];
            S[tidx(i, c)] = -a / S[tidx(i, i)];
        }
    }

#pragma unroll
    for (int k = 0; k < TRI; ++k) wout[g * TRI + k] = S[k];
#pragma unroll
    for (int j = 0; j < GS; ++j) muout[g * GS + j] = mu[j];
}

// ---------------------------------------------------------------------------
// Pass 3: out = W * (x - mu), per group. Same decomposition as pass 1.
// ---------------------------------------------------------------------------
__global__ __launch_bounds__(256, 2) void whiten_apply(const float* __restrict__ x,
                                                       const float* __restrict__ wmat,
                                                       const float* __restrict__ mu,
                                                       float* __restrict__ out) {
    const int b = blockIdx.x;
    const int g = blockIdx.y;

    float w[TRI], mv[GS];
#pragma unroll
    for (int k = 0; k < TRI; ++k) w[k] = wmat[g * TRI + k];
#pragma unroll
    for (int j = 0; j < GS; ++j) mv[j] = mu[g * GS + j];

    const size_t off0 = ((size_t)b * D_FEAT + (size_t)g * GS) * HW;
    const float* base = x + off0;
    float* obase = out + off0;

    for (int p = threadIdx.x; p < HW; p += 256) {
        float v[GS];
#pragma unroll
        for (int j = 0; j < GS; ++j) v[j] = base[(size_t)j * HW + p] - mv[j];
#pragma unroll
        for (int i = 0; i < GS; ++i) {
            float a = w[tidx(i, 0)] * v[0];
#pragma unroll
            for (int j = 1; j <= i; ++j) a = fmaf(w[tidx(i, j)], v[j], a);
            obase[(size_t)i * HW + p] = a;
        }
    }
}

extern "C" void kernel_launch(void* const* d_in, const int* in_sizes, int n_in,
                              void* d_out, int out_size, void* d_ws, size_t ws_size,
                              hipStream_t stream) {
    const float* x = (const float*)d_in[0];
    float* out = (float*)d_out;

    float* ws = (float*)d_ws;
    float* sums = ws;                   // 256 floats
    float* gram = ws + 256;             // 16*136 = 2176 floats
    float* wmat = ws + 256 + 2176;      // 2176 floats (packed W per group)
    float* muv  = wmat + 2176;          // 256 floats

    // accumulators must start at zero (ws is poisoned each call)
    hipMemsetAsync(ws, 0, (256 + 2176) * sizeof(float), stream);

    dim3 grid(M_BATCH, NGROUPS);
    whiten_stats<<<grid, 256, 0, stream>>>(x, sums, gram);
    whiten_solve<<<1, 64, 0, stream>>>(sums, gram, wmat, muv);
    whiten_apply<<<grid, 256, 0, stream>>>(x, wmat, muv, out);
}